// Round 1
// baseline (336.235 us; speedup 1.0000x reference)
//
#include <hip/hip_runtime.h>

#define EPSV 1e-8f
#define CENTER_VAR 0.1f
#define SIZE_VAR 0.2f
#define TILE 256

__device__ __forceinline__ float4 decode_box(float4 loc, float4 pr) {
    // cxcy = pr.xy + loc.xy * CENTER_VAR * pr.zw ; wh = pr.zw * exp(loc.zw * SIZE_VAR)
    float cx = pr.x + loc.x * CENTER_VAR * pr.z;
    float cy = pr.y + loc.y * CENTER_VAR * pr.w;
    float w  = pr.z * expf(loc.z * SIZE_VAR);
    float h  = pr.w * expf(loc.w * SIZE_VAR);
    float x0 = cx - w * 0.5f;
    float y0 = cy - h * 0.5f;
    // reference: mx = mn + wh
    return make_float4(x0, y0, x0 + w, y0 + h);
}

__device__ __forceinline__ float giou_pair(float4 A, float4 Bx) {
    float ix = fminf(A.z, Bx.z) - fmaxf(A.x, Bx.x);
    float iy = fminf(A.w, Bx.w) - fmaxf(A.y, Bx.y);
    float inter = fmaxf(ix, 0.f) * fmaxf(iy, 0.f);
    float area_a = (A.z - A.x) * (A.w - A.y);
    float area_b = (Bx.z - Bx.x) * (Bx.w - Bx.y);
    float uni = area_a + area_b - inter;
    float iou = inter / fmaxf(uni, EPSV);
    float ex = fmaxf(A.z, Bx.z) - fminf(A.x, Bx.x);
    float ey = fmaxf(A.w, Bx.w) - fminf(A.y, Bx.y);
    float enc = ex * ey;
    return iou - (enc - uni) / fmaxf(enc, EPSV);
}

// Kernel 1: per (b,p) compute masks, decode boxes, compact into per-batch lists.
__global__ void mask_decode_kernel(
    const float* __restrict__ conf,
    const float* __restrict__ loc,
    const int*   __restrict__ tconf,
    const float* __restrict__ tloc,
    const float* __restrict__ priors,
    int B, int P, int C,
    int* __restrict__ na, int* __restrict__ nt,
    float4* __restrict__ inf_boxes, float4* __restrict__ tgt_boxes) {
    int idx = blockIdx.x * blockDim.x + threadIdx.x;
    if (idx >= B * P) return;
    int b = idx / P;
    int p = idx - b * P;

    bool pos_t = tconf[idx] > 0;
    if (!pos_t) return;   // pos_infer requires pos_target too

    float4 pr = ((const float4*)priors)[p];

    // target box
    {
        float4 l = ((const float4*)tloc)[idx];
        int k = atomicAdd(&nt[b], 1);
        tgt_boxes[(size_t)b * P + k] = decode_box(l, pr);
    }

    // pos_infer: max_p > 0.5  <=>  sum(exp(l - max)) < 2 ; argmax > 0
    const float* cf = conf + (size_t)idx * C;
    float m = cf[0];
    int mi = 0;
    for (int c = 1; c < C; ++c) {
        float v = cf[c];
        if (v > m) { m = v; mi = c; }
    }
    float se = 0.f;
    for (int c = 0; c < C; ++c) se += expf(cf[c] - m);
    if (se < 2.0f && mi > 0) {
        float4 l = ((const float4*)loc)[idx];
        int k = atomicAdd(&na[b], 1);
        inf_boxes[(size_t)b * P + k] = decode_box(l, pr);
    }
}

// Kernel 2: per batch, sum GIoU over compacted (infer x target) pairs.
__global__ void pair_sum_kernel(
    const float4* __restrict__ inf_boxes,
    const float4* __restrict__ tgt_boxes,
    const int* __restrict__ na, const int* __restrict__ nt,
    float* __restrict__ s, int P) {
    int b = blockIdx.y;
    int nA = na[b];
    int nT = nt[b];
    __shared__ float4 tb[TILE];
    float acc = 0.f;
    for (int a0 = blockIdx.x * blockDim.x; a0 < nA; a0 += gridDim.x * blockDim.x) {
        int a = a0 + threadIdx.x;
        bool valid = a < nA;
        float4 A = valid ? inf_boxes[(size_t)b * P + a] : make_float4(0.f, 0.f, 0.f, 0.f);
        for (int t0 = 0; t0 < nT; t0 += TILE) {
            int cnt = min(TILE, nT - t0);
            __syncthreads();
            for (int i = threadIdx.x; i < cnt; i += (int)blockDim.x)
                tb[i] = tgt_boxes[(size_t)b * P + t0 + i];
            __syncthreads();
            if (valid) {
                for (int i = 0; i < cnt; ++i) acc += giou_pair(A, tb[i]);
            }
        }
    }
    // wave-64 reduce, one atomic per wave
    for (int off = 32; off > 0; off >>= 1) acc += __shfl_down(acc, off);
    if ((threadIdx.x & 63) == 0) atomicAdd(&s[b], acc);
}

// Kernel 3: final scalar.
__global__ void finalize_kernel(const float* __restrict__ s,
                                const int* __restrict__ na,
                                const int* __restrict__ nt,
                                int B, float* __restrict__ out) {
    if (threadIdx.x != 0 || blockIdx.x != 0) return;
    float tsum = 0.f, nsum = 0.f;
    for (int b = 0; b < B; ++b) {
        float ntf = (float)nt[b];
        bool bt = nt[b] > 0;
        bool ba = na[b] > 0;
        float term;
        if (bt && ba)       term = ntf - s[b] / fmaxf(ntf, 1.f);
        else if (bt != ba)  term = 1.f;
        else                term = 0.f;
        tsum += term;
        nsum += ntf;
    }
    out[0] = tsum / fmaxf(nsum, 1.f);
}

extern "C" void kernel_launch(void* const* d_in, const int* in_sizes, int n_in,
                              void* d_out, int out_size, void* d_ws, size_t ws_size,
                              hipStream_t stream) {
    const float* conf   = (const float*)d_in[0];
    const float* loc    = (const float*)d_in[1];
    const int*   tconf  = (const int*)  d_in[2];
    const float* tloc   = (const float*)d_in[3];
    const float* priors = (const float*)d_in[4];
    float* out = (float*)d_out;

    int P = in_sizes[4] / 4;          // priors: [P,4]
    int B = in_sizes[2] / P;          // target_confidence: [B,P]
    int C = in_sizes[0] / (B * P);    // confidence: [B,P,C]

    // workspace layout
    int*    na = (int*)d_ws;                        // [B]   (B<=16 assumed)
    int*    nt = na + 16;                           // [B]
    float*  s  = (float*)(na + 32);                 // [B]
    float4* inf_boxes = (float4*)((char*)d_ws + 256);
    float4* tgt_boxes = inf_boxes + (size_t)B * P;

    // zero the header (counters + accumulators)
    hipMemsetAsync(d_ws, 0, 256, stream);

    int total = B * P;
    mask_decode_kernel<<<(total + 255) / 256, 256, 0, stream>>>(
        conf, loc, tconf, tloc, priors, B, P, C, na, nt, inf_boxes, tgt_boxes);

    dim3 grid2((P + 255) / 256, B);
    pair_sum_kernel<<<grid2, 256, 0, stream>>>(inf_boxes, tgt_boxes, na, nt, s, P);

    finalize_kernel<<<1, 64, 0, stream>>>(s, na, nt, B, out);
}

// Round 2
// 167.376 us; speedup vs baseline: 2.0089x; 2.0089x over previous
//
#include <hip/hip_runtime.h>

#define EPSV 1e-8f
#define CENTER_VAR 0.1f
#define SIZE_VAR 0.2f
#define TILE 256

__device__ __forceinline__ float4 decode_box(float4 loc, float4 pr) {
    float cx = pr.x + loc.x * CENTER_VAR * pr.z;
    float cy = pr.y + loc.y * CENTER_VAR * pr.w;
    float w  = pr.z * __expf(loc.z * SIZE_VAR);
    float h  = pr.w * __expf(loc.w * SIZE_VAR);
    float x0 = cx - w * 0.5f;
    float y0 = cy - h * 0.5f;
    return make_float4(x0, y0, x0 + w, y0 + h);
}

__device__ __forceinline__ float giou_pair(float4 A, float4 Bx) {
    float ix = fminf(A.z, Bx.z) - fmaxf(A.x, Bx.x);
    float iy = fminf(A.w, Bx.w) - fmaxf(A.y, Bx.y);
    float inter = fmaxf(ix, 0.f) * fmaxf(iy, 0.f);
    float area_a = (A.z - A.x) * (A.w - A.y);
    float area_b = (Bx.z - Bx.x) * (Bx.w - Bx.y);
    float uni = area_a + area_b - inter;
    float iou = __fdividef(inter, fmaxf(uni, EPSV));
    float ex = fmaxf(A.z, Bx.z) - fminf(A.x, Bx.x);
    float ey = fmaxf(A.w, Bx.w) - fminf(A.y, Bx.y);
    float enc = ex * ey;
    return iou - __fdividef(enc - uni, fmaxf(enc, EPSV));
}

// Kernel 1: per (b,p) compute masks, decode boxes, compact into per-batch lists.
__global__ void mask_decode_kernel(
    const float* __restrict__ conf,
    const float* __restrict__ loc,
    const int*   __restrict__ tconf,
    const float* __restrict__ tloc,
    const float* __restrict__ priors,
    int B, int P, int C,
    int* __restrict__ na, int* __restrict__ nt,
    float4* __restrict__ inf_boxes, float4* __restrict__ tgt_boxes) {
    int idx = blockIdx.x * blockDim.x + threadIdx.x;
    if (idx >= B * P) return;
    int b = idx / P;
    int p = idx - b * P;

    if (tconf[idx] <= 0) return;   // pos_infer requires pos_target too

    float4 pr = ((const float4*)priors)[p];

    // target box
    {
        float4 l = ((const float4*)tloc)[idx];
        int k = atomicAdd(&nt[b], 1);
        tgt_boxes[(size_t)b * P + k] = decode_box(l, pr);
    }

    // pos_infer: max_p > 0.5  <=>  sum(exp(l - max)) < 2 ; argmax > 0
    const float* cf = conf + (size_t)idx * C;
    float m = cf[0];
    int mi = 0;
    for (int c = 1; c < C; ++c) {
        float v = cf[c];
        if (v > m) { m = v; mi = c; }
    }
    float se = 0.f;
    for (int c = 0; c < C; ++c) se += __expf(cf[c] - m);
    if (se < 2.0f && mi > 0) {
        float4 l = ((const float4*)loc)[idx];
        int k = atomicAdd(&na[b], 1);
        inf_boxes[(size_t)b * P + k] = decode_box(l, pr);
    }
}

// Kernel 2: thread-per-TARGET box; small infer-box list staged in LDS.
__global__ void pair_sum_kernel(
    const float4* __restrict__ inf_boxes,
    const float4* __restrict__ tgt_boxes,
    const int* __restrict__ na, const int* __restrict__ nt,
    float* __restrict__ s, int P) {
    int b = blockIdx.y;
    int nA = na[b];
    int nT = nt[b];
    if (nA == 0 || nT == 0) return;   // s[b] stays 0 from memset

    __shared__ float4 ab[TILE];
    int t = blockIdx.x * blockDim.x + threadIdx.x;
    bool valid = t < nT;
    float4 T = valid ? tgt_boxes[(size_t)b * P + t]
                     : make_float4(0.f, 0.f, 0.f, 0.f);

    float acc = 0.f;
    for (int a0 = 0; a0 < nA; a0 += TILE) {
        int cnt = min(TILE, nA - a0);
        __syncthreads();
        for (int i = threadIdx.x; i < cnt; i += (int)blockDim.x)
            ab[i] = inf_boxes[(size_t)b * P + a0 + i];
        __syncthreads();
        if (valid) {
            for (int i = 0; i < cnt; ++i) acc += giou_pair(ab[i], T);
        }
    }
    // wave-64 reduce, one atomic per wave
    for (int off = 32; off > 0; off >>= 1) acc += __shfl_down(acc, off);
    if ((threadIdx.x & 63) == 0) atomicAdd(&s[b], acc);
}

// Kernel 3: final scalar.
__global__ void finalize_kernel(const float* __restrict__ s,
                                const int* __restrict__ na,
                                const int* __restrict__ nt,
                                int B, float* __restrict__ out) {
    if (threadIdx.x != 0 || blockIdx.x != 0) return;
    float tsum = 0.f, nsum = 0.f;
    for (int b = 0; b < B; ++b) {
        float ntf = (float)nt[b];
        bool bt = nt[b] > 0;
        bool ba = na[b] > 0;
        float term;
        if (bt && ba)       term = ntf - s[b] / fmaxf(ntf, 1.f);
        else if (bt != ba)  term = 1.f;
        else                term = 0.f;
        tsum += term;
        nsum += ntf;
    }
    out[0] = tsum / fmaxf(nsum, 1.f);
}

extern "C" void kernel_launch(void* const* d_in, const int* in_sizes, int n_in,
                              void* d_out, int out_size, void* d_ws, size_t ws_size,
                              hipStream_t stream) {
    const float* conf   = (const float*)d_in[0];
    const float* loc    = (const float*)d_in[1];
    const int*   tconf  = (const int*)  d_in[2];
    const float* tloc   = (const float*)d_in[3];
    const float* priors = (const float*)d_in[4];
    float* out = (float*)d_out;

    int P = in_sizes[4] / 4;          // priors: [P,4]
    int B = in_sizes[2] / P;          // target_confidence: [B,P]
    int C = in_sizes[0] / (B * P);    // confidence: [B,P,C]

    // workspace layout
    int*    na = (int*)d_ws;                        // [B]   (B<=16 assumed)
    int*    nt = na + 16;                           // [B]
    float*  s  = (float*)(na + 32);                 // [B]
    float4* inf_boxes = (float4*)((char*)d_ws + 256);
    float4* tgt_boxes = inf_boxes + (size_t)B * P;

    // zero the header (counters + accumulators)
    hipMemsetAsync(d_ws, 0, 256, stream);

    int total = B * P;
    mask_decode_kernel<<<(total + 255) / 256, 256, 0, stream>>>(
        conf, loc, tconf, tloc, priors, B, P, C, na, nt, inf_boxes, tgt_boxes);

    dim3 grid2((P + 255) / 256, B);
    pair_sum_kernel<<<grid2, 256, 0, stream>>>(inf_boxes, tgt_boxes, na, nt, s, P);

    finalize_kernel<<<1, 64, 0, stream>>>(s, na, nt, B, out);
}

// Round 5
// 73.940 us; speedup vs baseline: 4.5474x; 2.2637x over previous
//
#include <hip/hip_runtime.h>

#define EPSV 1e-8f
#define CENTER_VAR 0.1f
#define SIZE_VAR 0.2f
#define MAXP 2048     // LDS infer-box capacity (P == 2048 in this problem)
#define BLK 1024

__device__ __forceinline__ float4 decode_box(float4 loc, float4 pr) {
    float cx = pr.x + loc.x * CENTER_VAR * pr.z;
    float cy = pr.y + loc.y * CENTER_VAR * pr.w;
    float w  = pr.z * __expf(loc.z * SIZE_VAR);
    float h  = pr.w * __expf(loc.w * SIZE_VAR);
    float x0 = cx - w * 0.5f;
    float y0 = cy - h * 0.5f;
    return make_float4(x0, y0, x0 + w, y0 + h);
}

__device__ __forceinline__ float giou_pair(float4 A, float4 Bx) {
    float ix = fminf(A.z, Bx.z) - fmaxf(A.x, Bx.x);
    float iy = fminf(A.w, Bx.w) - fmaxf(A.y, Bx.y);
    float inter = fmaxf(ix, 0.f) * fmaxf(iy, 0.f);
    float area_a = (A.z - A.x) * (A.w - A.y);
    float area_b = (Bx.z - Bx.x) * (Bx.w - Bx.y);
    float uni = area_a + area_b - inter;
    float iou = __fdividef(inter, fmaxf(uni, EPSV));
    float ex = fmaxf(A.z, Bx.z) - fminf(A.x, Bx.x);
    float ey = fmaxf(A.w, Bx.w) - fminf(A.y, Bx.y);
    float enc = ex * ey;
    return iou - __fdividef(enc - uni, fmaxf(enc, EPSV));
}

// One block per batch. Phase 1: compact the rare pos_infer boxes into LDS
// (LDS atomics only). Phase 2: thread-per-target, decode target in regs,
// loop over the small LDS infer list. Block-reduce s and nt; plain stores.
__global__ __launch_bounds__(BLK) void fused_kernel(
    const float* __restrict__ conf,
    const float* __restrict__ loc,
    const int*   __restrict__ tconf,
    const float* __restrict__ tloc,
    const float* __restrict__ priors,
    int P, int C,
    float* __restrict__ term_out, float* __restrict__ nt_out) {
    int b = blockIdx.x;
    __shared__ float4 ab[MAXP];
    __shared__ int nA_sh;
    __shared__ float red_f[BLK / 64];
    __shared__ int   red_i[BLK / 64];
    if (threadIdx.x == 0) nA_sh = 0;
    __syncthreads();

    const size_t base = (size_t)b * P;

    // ---- Phase 1: pos_infer detection + LDS compaction ----
    for (int p = threadIdx.x; p < P; p += BLK) {
        size_t idx = base + p;
        if (tconf[idx] > 0) {              // pos_infer requires pos_target
            const float* cf = conf + idx * C;
            float m; int mi; float se;
            if (C == 21) {                 // unrolled fast path: 21 loads in flight
                float v[21];
                #pragma unroll
                for (int c = 0; c < 21; ++c) v[c] = cf[c];
                m = v[0]; mi = 0;
                #pragma unroll
                for (int c = 1; c < 21; ++c) { if (v[c] > m) { m = v[c]; mi = c; } }
                se = 0.f;
                #pragma unroll
                for (int c = 0; c < 21; ++c) se += __expf(v[c] - m);
            } else {
                m = cf[0]; mi = 0;
                for (int c = 1; c < C; ++c) { float v = cf[c]; if (v > m) { m = v; mi = c; } }
                se = 0.f;
                for (int c = 0; c < C; ++c) se += __expf(cf[c] - m);
            }
            // max_p > 0.5  <=>  sum(exp(l - max)) < 2 ; argmax > 0
            if (se < 2.0f && mi > 0) {
                float4 l  = ((const float4*)loc)[idx];
                float4 pr = ((const float4*)priors)[p];
                int k = atomicAdd(&nA_sh, 1);   // LDS atomic — cheap
                if (k < MAXP) ab[k] = decode_box(l, pr);
            }
        }
    }
    __syncthreads();
    int nA = nA_sh;

    // ---- Phase 2: thread-per-target vs LDS infer list ----
    float acc = 0.f;
    int   ntc = 0;
    for (int p = threadIdx.x; p < P; p += BLK) {
        size_t idx = base + p;
        if (tconf[idx] > 0) {
            ++ntc;
            float4 l  = ((const float4*)tloc)[idx];
            float4 pr = ((const float4*)priors)[p];
            float4 T = decode_box(l, pr);
            for (int i = 0; i < nA; ++i) acc += giou_pair(ab[i], T);
        }
    }

    // ---- Block reduction ----
    int lane = threadIdx.x & 63, wid = threadIdx.x >> 6;
    for (int off = 32; off > 0; off >>= 1) {
        acc += __shfl_down(acc, off);
        ntc += __shfl_down(ntc, off);
    }
    if (lane == 0) { red_f[wid] = acc; red_i[wid] = ntc; }
    __syncthreads();
    if (threadIdx.x == 0) {
        float s = 0.f; int nt = 0;
        for (int w = 0; w < BLK / 64; ++w) { s += red_f[w]; nt += red_i[w]; }
        float ntf = (float)nt;
        bool bt = nt > 0, ba = nA > 0;
        float term = (bt && ba) ? (ntf - s / fmaxf(ntf, 1.f))
                                : ((bt != ba) ? 1.f : 0.f);
        term_out[b] = term;   // plain store — no memset needed
        nt_out[b]   = ntf;
    }
}

__global__ void finalize_kernel(const float* __restrict__ term,
                                const float* __restrict__ ntf,
                                int B, float* __restrict__ out) {
    if (threadIdx.x != 0 || blockIdx.x != 0) return;
    float tsum = 0.f, nsum = 0.f;
    for (int b = 0; b < B; ++b) { tsum += term[b]; nsum += ntf[b]; }
    out[0] = tsum / fmaxf(nsum, 1.f);
}

extern "C" void kernel_launch(void* const* d_in, const int* in_sizes, int n_in,
                              void* d_out, int out_size, void* d_ws, size_t ws_size,
                              hipStream_t stream) {
    const float* conf   = (const float*)d_in[0];
    const float* loc    = (const float*)d_in[1];
    const int*   tconf  = (const int*)  d_in[2];
    const float* tloc   = (const float*)d_in[3];
    const float* priors = (const float*)d_in[4];
    float* out = (float*)d_out;

    int P = in_sizes[4] / 4;          // priors: [P,4]
    int B = in_sizes[2] / P;          // target_confidence: [B,P]
    int C = in_sizes[0] / (B * P);    // confidence: [B,P,C]

    float* term = (float*)d_ws;       // [B] — written unconditionally
    float* ntf  = term + 64;          // [B]

    fused_kernel<<<B, BLK, 0, stream>>>(conf, loc, tconf, tloc, priors,
                                        P, C, term, ntf);
    finalize_kernel<<<1, 64, 0, stream>>>(term, ntf, B, out);
}

// Round 6
// 69.597 us; speedup vs baseline: 4.8312x; 1.0624x over previous
//
#include <hip/hip_runtime.h>

#define EPSV 1e-8f
#define CENTER_VAR 0.1f
#define SIZE_VAR 0.2f
#define TPB 256
#define ATILE 512   // LDS infer-list staging chunk (float4)

__device__ __forceinline__ float4 decode_box(float4 loc, float4 pr) {
    float cx = pr.x + loc.x * CENTER_VAR * pr.z;
    float cy = pr.y + loc.y * CENTER_VAR * pr.w;
    float w  = pr.z * __expf(loc.z * SIZE_VAR);
    float h  = pr.w * __expf(loc.w * SIZE_VAR);
    float x0 = cx - w * 0.5f;
    float y0 = cy - h * 0.5f;
    return make_float4(x0, y0, x0 + w, y0 + h);
}

__device__ __forceinline__ float giou_pair(float4 A, float4 Bx) {
    float ix = fminf(A.z, Bx.z) - fmaxf(A.x, Bx.x);
    float iy = fminf(A.w, Bx.w) - fmaxf(A.y, Bx.y);
    float inter = fmaxf(ix, 0.f) * fmaxf(iy, 0.f);
    float area_a = (A.z - A.x) * (A.w - A.y);
    float area_b = (Bx.z - Bx.x) * (Bx.w - Bx.y);
    float uni = area_a + area_b - inter;
    float iou = __fdividef(inter, fmaxf(uni, EPSV));
    float ex = fmaxf(A.z, Bx.z) - fminf(A.x, Bx.x);
    float ey = fmaxf(A.w, Bx.w) - fminf(A.y, Bx.y);
    float enc = ex * ey;
    return iou - __fdividef(enc - uni, fmaxf(enc, EPSV));
}

// k1: thread per (b,p). nt via ballot+block-reduce (1 atomic/block).
// Rare pos_infer boxes decoded and appended to per-batch global list.
// Requires P % TPB == 0 so b is block-uniform (holds: P=2048).
__global__ __launch_bounds__(TPB) void mask_kernel(
    const float* __restrict__ conf,
    const float* __restrict__ loc,
    const int*   __restrict__ tconf,
    const float* __restrict__ priors,
    int total, int P, int C,
    int* __restrict__ na, int* __restrict__ nt,
    float4* __restrict__ inf_boxes) {
    int idx = blockIdx.x * TPB + threadIdx.x;
    bool live = idx < total;
    int b = idx / P;
    int p = idx - b * P;

    bool pos_t = live && (tconf[idx] > 0);

    // --- nt count: ballot per wave, one atomic per block ---
    unsigned long long bm = __ballot(pos_t);
    __shared__ int wcnt[TPB / 64];
    int lane = threadIdx.x & 63, wid = threadIdx.x >> 6;
    if (lane == 0) wcnt[wid] = __popcll(bm);
    __syncthreads();
    if (threadIdx.x == 0) {
        int c = 0;
        #pragma unroll
        for (int w = 0; w < TPB / 64; ++w) c += wcnt[w];
        if (c) atomicAdd(&nt[b], c);
    }

    if (!pos_t) return;

    // --- pos_infer: max_p > 0.5 <=> sum(exp(l-max)) < 2 ; argmax > 0 ---
    const float* cf = conf + (size_t)idx * C;
    float m; int mi; float se;
    if (C == 21) {
        float v[21];
        #pragma unroll
        for (int c = 0; c < 21; ++c) v[c] = cf[c];
        m = v[0]; mi = 0;
        #pragma unroll
        for (int c = 1; c < 21; ++c) { if (v[c] > m) { m = v[c]; mi = c; } }
        se = 0.f;
        #pragma unroll
        for (int c = 0; c < 21; ++c) se += __expf(v[c] - m);
    } else {
        m = cf[0]; mi = 0;
        for (int c = 1; c < C; ++c) { float v = cf[c]; if (v > m) { m = v; mi = c; } }
        se = 0.f;
        for (int c = 0; c < C; ++c) se += __expf(cf[c] - m);
    }
    if (se < 2.0f && mi > 0) {
        float4 l  = ((const float4*)loc)[idx];
        float4 pr = ((const float4*)priors)[p];
        int k = atomicAdd(&na[b], 1);          // rare (~tens/batch)
        inf_boxes[(size_t)b * P + k] = decode_box(l, pr);
    }
}

// k2: thread per (b,p) target; infer list staged in LDS chunks.
__global__ __launch_bounds__(TPB) void pair_kernel(
    const float4* __restrict__ inf_boxes,
    const int*   __restrict__ tconf,
    const float* __restrict__ tloc,
    const float* __restrict__ priors,
    const int* __restrict__ na,
    float* __restrict__ s,
    int total, int P) {
    int idx = blockIdx.x * TPB + threadIdx.x;
    bool live = idx < total;
    int b = idx / P;
    int p = idx - b * P;
    int nA = na[b];                      // block-uniform

    __shared__ float4 ab[ATILE];
    bool pos_t = live && (tconf[idx] > 0);
    float4 T = make_float4(0.f, 0.f, 0.f, 0.f);
    if (pos_t) {
        float4 l  = ((const float4*)tloc)[idx];
        float4 pr = ((const float4*)priors)[p];
        T = decode_box(l, pr);
    }

    float acc = 0.f;
    for (int a0 = 0; a0 < nA; a0 += ATILE) {
        int cnt = min(ATILE, nA - a0);
        __syncthreads();
        for (int i = threadIdx.x; i < cnt; i += TPB)
            ab[i] = inf_boxes[(size_t)b * P + a0 + i];
        __syncthreads();
        if (pos_t) {
            for (int i = 0; i < cnt; ++i) acc += giou_pair(ab[i], T);
        }
    }

    // block reduce, one atomic per block
    for (int off = 32; off > 0; off >>= 1) acc += __shfl_down(acc, off);
    __shared__ float wsum[TPB / 64];
    int lane = threadIdx.x & 63, wid = threadIdx.x >> 6;
    if (lane == 0) wsum[wid] = acc;
    __syncthreads();
    if (threadIdx.x == 0) {
        float t = 0.f;
        #pragma unroll
        for (int w = 0; w < TPB / 64; ++w) t += wsum[w];
        atomicAdd(&s[b], t);
    }
}

__global__ void finalize_kernel(const float* __restrict__ s,
                                const int* __restrict__ na,
                                const int* __restrict__ nt,
                                int B, float* __restrict__ out) {
    if (threadIdx.x != 0 || blockIdx.x != 0) return;
    float tsum = 0.f, nsum = 0.f;
    for (int b = 0; b < B; ++b) {
        float ntf = (float)nt[b];
        bool bt = nt[b] > 0;
        bool ba = na[b] > 0;
        float term;
        if (bt && ba)       term = ntf - s[b] / fmaxf(ntf, 1.f);
        else if (bt != ba)  term = 1.f;
        else                term = 0.f;
        tsum += term;
        nsum += ntf;
    }
    out[0] = tsum / fmaxf(nsum, 1.f);
}

extern "C" void kernel_launch(void* const* d_in, const int* in_sizes, int n_in,
                              void* d_out, int out_size, void* d_ws, size_t ws_size,
                              hipStream_t stream) {
    const float* conf   = (const float*)d_in[0];
    const float* loc    = (const float*)d_in[1];
    const int*   tconf  = (const int*)  d_in[2];
    const float* tloc   = (const float*)d_in[3];
    const float* priors = (const float*)d_in[4];
    float* out = (float*)d_out;

    int P = in_sizes[4] / 4;          // priors: [P,4]
    int B = in_sizes[2] / P;          // target_confidence: [B,P]
    int C = in_sizes[0] / (B * P);    // confidence: [B,P,C]

    // ws header: na[16] int | nt[16] int | s[16] float  (256 B), then boxes
    int*    na = (int*)d_ws;
    int*    nt = na + 16;
    float*  s  = (float*)(na + 32);
    float4* inf_boxes = (float4*)((char*)d_ws + 256);

    hipMemsetAsync(d_ws, 0, 256, stream);

    int total = B * P;
    int grid = (total + TPB - 1) / TPB;   // 64 blocks for B=8,P=2048
    mask_kernel<<<grid, TPB, 0, stream>>>(conf, loc, tconf, priors,
                                          total, P, C, na, nt, inf_boxes);
    pair_kernel<<<grid, TPB, 0, stream>>>(inf_boxes, tconf, tloc, priors,
                                          na, s, total, P);
    finalize_kernel<<<1, 64, 0, stream>>>(s, na, nt, B, out);
}